// Round 11
// baseline (10443.572 us; speedup 1.0000x reference)
//
#include <hip/hip_runtime.h>
#include <stdint.h>

// ---------------------------------------------------------------------------
// SimpleRNN: bidirectional LSTM encoder (S=256) + autoregressive decoder (T=128)
// B=128, D=256, H=1024. Persistent kernels, fence-free flag grid barriers.
// R11 = R10 fixed: (1) mlp32 ring slot stride 4096us (was 2048 -> overlap bug);
// (2) phase-1 raws ALL preloaded before the h burst, converted after it, so
// vmcnt FIFO consumption never drains the 40-op h prefetch (phase 1 VMEM-free).
// W ring depth-2, h ring depth-5, mlp ring depth-4. 144 KB dynamic LDS.
// 3-term split-bf16 MFMA (Wh*Ah + Wh*Al + Wl*Ah), f32 accum/gates.
// ---------------------------------------------------------------------------

typedef __attribute__((ext_vector_type(8))) short bfx8;
typedef __attribute__((ext_vector_type(4))) float f32x4;
typedef __attribute__((ext_vector_type(4))) unsigned short u16x4;
typedef unsigned short ushort_t;
typedef unsigned long long u64;

#define NWG 256
#define MFMA(a,b,c) __builtin_amdgcn_mfma_f32_16x16x32_bf16((a),(b),(c),0,0,0)
#define WAITVM(N) { asm volatile("s_waitcnt vmcnt(" #N ")" ::: "memory"); __builtin_amdgcn_sched_barrier(0); }
#define WAITLG(N) { asm volatile("s_waitcnt lgkmcnt(" #N ")" ::: "memory"); __builtin_amdgcn_sched_barrier(0); }
#define SBAR()    { __builtin_amdgcn_s_barrier(); __builtin_amdgcn_sched_barrier(0); }
#define SCHED0()  __builtin_amdgcn_sched_barrier(0)

__device__ __forceinline__ unsigned short f2bf(float f){
  unsigned u = __float_as_uint(f);
  u += 0x7FFFu + ((u >> 16) & 1u);          // round-to-nearest-even
  return (unsigned short)(u >> 16);
}
__device__ __forceinline__ float bf2f(unsigned short h){
  return __uint_as_float(((unsigned)h) << 16);
}
__device__ __forceinline__ float sigm(float x){ return 1.f/(1.f + __expf(-x)); }
__device__ __forceinline__ float tanh_(float x){ return 1.f - 2.f/(__expf(2.f*x) + 1.f); }

// plain (L1+L2 cached) async global->LDS: immutable weights
__device__ __forceinline__ void stage16(const void* g, void* l){
  __builtin_amdgcn_global_load_lds((const __attribute__((address_space(1))) void*)g,
                                   (__attribute__((address_space(3))) void*)l,
                                   16, 0, 0);
}
// agent-coherent (SC0|SC1 = 0x11, L3-served): mutable cross-XCD data
__device__ __forceinline__ void stage16c(const void* g, void* l){
  __builtin_amdgcn_global_load_lds((const __attribute__((address_space(1))) void*)g,
                                   (__attribute__((address_space(3))) void*)l,
                                   16, 0, 0x11);
}

// coherent 16B load (2 x u64 agent-relaxed atomics)
__device__ __forceinline__ bfx8 ld16c(const ushort_t* p){
  const u64* q = (const u64*)p;
  u64 a = __hip_atomic_load(q,     __ATOMIC_RELAXED, __HIP_MEMORY_SCOPE_AGENT);
  u64 b = __hip_atomic_load(q + 1, __ATOMIC_RELAXED, __HIP_MEMORY_SCOPE_AGENT);
  union { u64 u[2]; bfx8 v; } x; x.u[0] = a; x.u[1] = b; return x.v;
}
__device__ __forceinline__ void sth2(ushort_t* p, unsigned short v){
  __hip_atomic_store(p, v, __ATOMIC_RELAXED, __HIP_MEMORY_SCOPE_AGENT);
}

// two f32x4 (8 consecutive f32) -> hi/lo bf16 planes
__device__ __forceinline__ void cvt2(const f32x4& a, const f32x4& b, bfx8& hi, bfx8& lo){
#pragma unroll
  for (int j = 0; j < 4; ++j){
    unsigned short h0 = f2bf(a[j]);
    unsigned short h1 = f2bf(b[j]);
    hi[j]   = (short)h0; lo[j]   = (short)f2bf(a[j] - bf2f(h0));
    hi[4+j] = (short)h1; lo[4+j] = (short)f2bf(b[j] - bf2f(h1));
  }
}

// ---------------------------------------------------------------------------
// Plain fence-free grid barrier (wave0 scans).
// ---------------------------------------------------------------------------
__device__ __forceinline__ void bar(unsigned* flags, int nflags, int me, unsigned gen){
  __syncthreads();                       // drains vmcnt(0): all stores done
  if (threadIdx.x == 0)
    __hip_atomic_store(&flags[me], gen, __ATOMIC_RELAXED, __HIP_MEMORY_SCOPE_AGENT);
  if (threadIdx.x < 64){
    const int l = threadIdx.x;
    for (;;){
      unsigned mn = 0xFFFFFFFFu;
      for (int o = l; o < nflags; o += 64){
        unsigned v = __hip_atomic_load(&flags[o], __ATOMIC_RELAXED, __HIP_MEMORY_SCOPE_AGENT);
        mn = mn < v ? mn : v;
      }
      if (__all((int)(mn >= gen))) break;
      __builtin_amdgcn_s_sleep(1);
    }
  }
  __syncthreads();
}

// ---------------------------------------------------------------------------
// Prefetching barrier: after the entry s_barrier, waves 0/1 issue next step's
// 2 W-chunks (slots 0/1) while wave3 stores the flag and spin-scans.
// ---------------------------------------------------------------------------
struct WPre {
  const ushort_t* pj[8];
  ushort_t* ldsb[2];
  bool active;                           // wv < 2
};
__device__ __forceinline__ void wpre_issue(const WPre& w){
  if (!w.active) return;
#pragma unroll
  for (int bp = 0; bp < 2; ++bp)
#pragma unroll
    for (int j = 0; j < 8; ++j)
      stage16(w.pj[j] + bp*64, w.ldsb[bp] + j*512);
}
__device__ __forceinline__ void bar_pf(unsigned* flags, int nflags, int me,
                                       unsigned gen, const WPre& w, bool pf){
  WAITLG(0); WAITVM(0);                  // own h-stores drained
  SBAR();                                // whole WG drained
  if (pf) wpre_issue(w);                 // waves 0/1: 16 W loads in flight
  if (threadIdx.x == 192)
    __hip_atomic_store(&flags[me], gen, __ATOMIC_RELAXED, __HIP_MEMORY_SCOPE_AGENT);
  if ((threadIdx.x >> 6) == 3){
    const int l = threadIdx.x & 63;
    for (;;){
      unsigned mn = 0xFFFFFFFFu;
      for (int o = l; o < nflags; o += 64){
        unsigned v = __hip_atomic_load(&flags[o], __ATOMIC_RELAXED, __HIP_MEMORY_SCOPE_AGENT);
        mn = mn < v ? mn : v;
      }
      if (__all((int)(mn >= gen))) break;
      __builtin_amdgcn_s_sleep(1);
    }
  }
  SBAR();
}

struct Frags { bfx8 awh0, awh1, awl0, awl1, bh0, bh1, bl0, bl1; };

// ---------------------------------------------------------------------------
// One LSTM cell step. Phase 1 (k<256, 4 chunks): ALL raws preloaded before
// the h burst, converted after it (vmcnt never drains the h prefetch), then
// a VMEM-free staging loop. Phase 2 (chunks 4..19): W ring depth-2
// (@16384us), h ring depth-5 (@32768us) fully issued at entry + refilled.
// P1 region @0 (16384 us). LDS total 73728 us = 144 KB.
// ---------------------------------------------------------------------------
template<int ENC>
__device__ __forceinline__ void cell_step(
    const float*    __restrict__ Wih,   // [4096][256] f32 original (this dir)
    const ushort_t* __restrict__ WhH,   // [4096][1024] bf16 hi (this dir)
    const ushort_t* __restrict__ WhL,   // lo
    const float*    __restrict__ bias,  // [4096] f32 (original order)
    const float*    __restrict__ xsl,   // ENC: x + tt*256 (row stride 65536)
    const ushort_t* __restrict__ iph,   // DEC: [128][256] hi
    const ushort_t* __restrict__ ipl,   // DEC: lo
    const ushort_t* __restrict__ hh,    // h hi source (+dir*1024), stride 2048
    const ushort_t* __restrict__ hl,    // h lo source
    ushort_t* __restrict__ outh, ushort_t* __restrict__ outl,
    float (&creg)[2][2],
    int r0, int n0, int b0, ushort_t* LDS)
{
  const int tid  = threadIdx.x;
  const int lane = tid & 63;
  const int wv   = tid >> 6;
  const int wm   = wv >> 1, wn = wv & 1;
  const int lr   = tid >> 3;               // phase-1 staging row 0..31
  const int lc   = tid & 7;
  const int cb   = lane >> 4;
  const int fr   = lane & 15;
  const int sc8  = lc ^ (lr & 7);          // phase-1 pre-swizzled source chunk
  const int sx   = fr & 7;
  const int rwa0 = wm*32 + fr, rwa1 = rwa0 + 16;
  const int rwb0 = wn*32 + fr, rwb1 = rwb0 + 16;

  // ---- phase-1 source pointers ----
  const int ra = r0 + lr, rb = ra + 32;
  const float* wih0 = Wih + (size_t)((ra & 3)*1024 + (ra >> 2))*256 + sc8*8;
  const float* wih1 = Wih + (size_t)((rb & 3)*1024 + (rb >> 2))*256 + sc8*8;
  const float *xs0 = nullptr, *xs1 = nullptr;
  const ushort_t *ih0 = nullptr, *ih1 = nullptr, *il0 = nullptr, *il1 = nullptr;
  if (ENC){
    xs0 = xsl + (size_t)(b0 + lr)*65536 + sc8*8;
    xs1 = xs0 + (size_t)32*65536;
  } else {
    ih0 = iph + (size_t)(b0 + lr)*256 + sc8*8;  ih1 = ih0 + 32*256;
    il0 = ipl + (size_t)(b0 + lr)*256 + sc8*8;  il1 = il0 + 32*256;
  }

  // ---- phase-2 staging: wave wv stages its plane ----
  const ushort_t* sb; size_t sstr; int srow0;
  if      (wv == 0){ sb = WhH; sstr = 1024; srow0 = r0; }
  else if (wv == 1){ sb = WhL; sstr = 1024; srow0 = r0; }
  else if (wv == 2){ sb = hh;  sstr = 2048; srow0 = b0; }
  else             { sb = hl;  sstr = 2048; srow0 = b0; }
  const int srw = lane >> 3;
  const int sg  = (lane & 7) ^ srw;        // swizzled source granule
  const ushort_t* pj[8];
#pragma unroll
  for (int j = 0; j < 8; ++j)
    pj[j] = sb + (size_t)(srow0 + j*8 + srw)*sstr + sg*8;

  auto ISSUE_W = [&](int c, int s){        // waves 0/1 only
    const int ko = (c - 4)*64;
    ushort_t* d = LDS + 16384 + s*8192 + (wv & 1)*4096;
#pragma unroll
    for (int j = 0; j < 8; ++j)
      stage16(pj[j] + ko, d + j*512);
  };
  auto ISSUE_H = [&](int c, int s){        // waves 2/3 only
    const int ko = (c - 4)*64;
    ushort_t* d = LDS + 32768 + s*8192 + (wv & 1)*4096;
#pragma unroll
    for (int j = 0; j < 8; ++j)
      stage16c(pj[j] + ko, d + j*512);
  };

  f32x4 acc[2][2] = {};
  auto rdf = [&](const ushort_t* wb, const ushort_t* ab, int ks, Frags& f){
    const int ga = (((ks << 2) + cb) ^ sx) << 3;
    f.awh0 = *(const bfx8*)(wb +        rwa0*64 + ga);
    f.awh1 = *(const bfx8*)(wb +        rwa1*64 + ga);
    f.awl0 = *(const bfx8*)(wb + 4096 + rwa0*64 + ga);
    f.awl1 = *(const bfx8*)(wb + 4096 + rwa1*64 + ga);
    f.bh0  = *(const bfx8*)(ab +        rwb0*64 + ga);
    f.bh1  = *(const bfx8*)(ab +        rwb1*64 + ga);
    f.bl0  = *(const bfx8*)(ab + 4096 + rwb0*64 + ga);
    f.bl1  = *(const bfx8*)(ab + 4096 + rwb1*64 + ga);
  };
  auto mm12 = [&](const Frags& f){
    acc[0][0] = MFMA(f.awh0, f.bh0, acc[0][0]);
    acc[0][0] = MFMA(f.awh0, f.bl0, acc[0][0]);
    acc[0][0] = MFMA(f.awl0, f.bh0, acc[0][0]);
    acc[0][1] = MFMA(f.awh0, f.bh1, acc[0][1]);
    acc[0][1] = MFMA(f.awh0, f.bl1, acc[0][1]);
    acc[0][1] = MFMA(f.awl0, f.bh1, acc[0][1]);
    acc[1][0] = MFMA(f.awh1, f.bh0, acc[1][0]);
    acc[1][0] = MFMA(f.awh1, f.bl0, acc[1][0]);
    acc[1][0] = MFMA(f.awl1, f.bh0, acc[1][0]);
    acc[1][1] = MFMA(f.awh1, f.bh1, acc[1][1]);
    acc[1][1] = MFMA(f.awh1, f.bl1, acc[1][1]);
    acc[1][1] = MFMA(f.awl1, f.bh1, acc[1][1]);
  };

  // ---- phase-1 preload: raws for ALL 4 chunks FIRST (older than h burst) ----
  f32x4 rw[4][4];                          // Wih f32 (both row groups)
  f32x4 rx[4][4];                          // ENC x f32
  bfx8  di[4][4];                          // DEC inp bf16
#pragma unroll
  for (int c = 0; c < 4; ++c){
    const int kc = c*64;
    rw[c][0] = *(const f32x4*)(wih0 + kc);  rw[c][1] = *(const f32x4*)(wih0 + kc + 4);
    rw[c][2] = *(const f32x4*)(wih1 + kc);  rw[c][3] = *(const f32x4*)(wih1 + kc + 4);
    if (ENC){
      rx[c][0] = *(const f32x4*)(xs0 + kc); rx[c][1] = *(const f32x4*)(xs0 + kc + 4);
      rx[c][2] = *(const f32x4*)(xs1 + kc); rx[c][3] = *(const f32x4*)(xs1 + kc + 4);
    } else {
      di[c][0] = ld16c(ih0 + kc);  di[c][1] = ld16c(ih1 + kc);
      di[c][2] = ld16c(il0 + kc);  di[c][3] = ld16c(il1 + kc);
    }
  }
  SCHED0();                                // pin: raws before h burst
  if (wv >= 2){
#pragma unroll
    for (int s = 0; s < 5; ++s)
      ISSUE_H(4 + s, s);                   // 40 h ops, youngest in FIFO
  }
  SCHED0();                                // pin: h burst before conversions
  // conversions: consumption waits are vmcnt<=(40+k) -> h never drained
  bfx8 swh[4][2], swl[4][2], sah[4][2], sal[4][2];
#pragma unroll
  for (int c = 0; c < 4; ++c){
    cvt2(rw[c][0], rw[c][1], swh[c][0], swl[c][0]);
    cvt2(rw[c][2], rw[c][3], swh[c][1], swl[c][1]);
    if (ENC){
      cvt2(rx[c][0], rx[c][1], sah[c][0], sal[c][0]);
      cvt2(rx[c][2], rx[c][3], sah[c][1], sal[c][1]);
    } else {
      sah[c][0] = di[c][0]; sah[c][1] = di[c][1];
      sal[c][0] = di[c][2]; sal[c][1] = di[c][3];
    }
  }

  // ---- phase 1: chunks 0..3 (VMEM-free; h burst flying underneath) ----
#pragma unroll
  for (int c = 0; c < 4; ++c){
    *(bfx8*)(LDS +         lr    *64 + lc*8) = swh[c][0];
    *(bfx8*)(LDS +        (lr+32)*64 + lc*8) = swh[c][1];
    *(bfx8*)(LDS + 4096 +  lr    *64 + lc*8) = swl[c][0];
    *(bfx8*)(LDS + 4096 + (lr+32)*64 + lc*8) = swl[c][1];
    *(bfx8*)(LDS + 8192 +  lr    *64 + lc*8) = sah[c][0];
    *(bfx8*)(LDS + 8192 + (lr+32)*64 + lc*8) = sah[c][1];
    *(bfx8*)(LDS + 12288 + lr    *64 + lc*8) = sal[c][0];
    *(bfx8*)(LDS + 12288 +(lr+32)*64 + lc*8) = sal[c][1];
    WAITLG(0); SBAR();
    Frags f0, f1;
    rdf(LDS, LDS + 8192, 0, f0);
    rdf(LDS, LDS + 8192, 1, f1);
    WAITLG(8);
    mm12(f0);
    WAITLG(0); SBAR();
    mm12(f1);
  }

  // ---- phase 2: chunks 4..19; W ring(2), h ring(5) ----
  int hcs = 0, his = 0;
  for (int i = 4; i <= 19; ++i){
    if (wv < 2){
      if (i <= 18) { WAITVM(8); } else { WAITVM(0); }
    } else {
      if      (i <= 15) { WAITVM(32); }
      else if (i == 16) { WAITVM(24); }
      else if (i == 17) { WAITVM(16); }
      else if (i == 18) { WAITVM(8); }
      else              { WAITVM(0); }
    }
    SBAR();                                  // chunk i staged by all waves
    const ushort_t* wb = LDS + 16384 + (i & 1)*8192;
    const ushort_t* ab = LDS + 32768 + hcs*8192;
    Frags f0, f1;
    rdf(wb, ab, 0, f0);
    rdf(wb, ab, 1, f1);
    WAITLG(8);
    mm12(f0);
    WAITLG(0); SBAR();                       // all reads done -> slots free
    if (wv < 2){ if (i <= 17) ISSUE_W(i + 2, i & 1); }
    else       { if (i <= 14) ISSUE_H(i + 5, his); }
    mm12(f1);
    hcs = (hcs == 4) ? 0 : hcs + 1;
    his = (his == 4) ? 0 : his + 1;
  }

  // ---- epilogue: gates -> c (regs), h -> global hi/lo planes (coherent) ----
#pragma unroll
  for (int m = 0; m < 2; ++m){
    const int n = n0 + wm*8 + m*4 + cb;
    const float bi_ = bias[n];
    const float bf_ = bias[1024 + n];
    const float bg_ = bias[2048 + n];
    const float bo_ = bias[3072 + n];
#pragma unroll
    for (int nb = 0; nb < 2; ++nb){
      const int b = b0 + wn*32 + nb*16 + fr;
      float gi = acc[m][nb][0] + bi_;
      float gf = acc[m][nb][1] + bf_;
      float gg = acc[m][nb][2] + bg_;
      float go = acc[m][nb][3] + bo_;
      float c_new = sigm(gf)*creg[m][nb] + sigm(gi)*tanh_(gg);
      float h_new = sigm(go)*tanh_(c_new);
      creg[m][nb] = c_new;
      unsigned short hi = f2bf(h_new);
      sth2(&outh[(size_t)b*2048 + n], hi);
      sth2(&outl[(size_t)b*2048 + n], f2bf(h_new - bf2f(hi)));
    }
  }
}

// ---------------------------------------------------------------------------
// Decoder MLP: 32 WGs, 32d x 32b tile; K=2048 over 4 waves (512 each, 16
// chunks of 32, wave-private depth-4 ring, slot = 4096 us); LDS combine.
// LDS us: partials @0 (8192), ring @8192 + wv*16384 + s*4096.
// ---------------------------------------------------------------------------
__device__ __forceinline__ void mlp32(
    const ushort_t* __restrict__ hch, const ushort_t* __restrict__ hcl,
    const ushort_t* __restrict__ mWh, const ushort_t* __restrict__ mWl,
    const float* __restrict__ mb, float* __restrict__ dout,
    ushort_t* __restrict__ inph, ushort_t* __restrict__ inpl,
    int wg, int t, ushort_t* LDS)
{
  const int tid = threadIdx.x, lane = tid & 63, wv = tid >> 6;
  const int d0 = (wg >> 2)*32, b0 = (wg & 3)*32;
  const int kb = wv*512;
  const int srw2 = lane >> 2;              // row within 16-row sub-block
  const int pg   = lane & 3;               // physical k-granule

  const ushort_t* base[4] = { mWh, mWl, hch, hcl };
  const int rb0[4] = { d0, d0, b0, b0 };
  const ushort_t* sp[8];
#pragma unroll
  for (int j = 0; j < 8; ++j){
    const int p = j >> 1, sub = j & 1;
    const int rl = sub*16 + srw2;
    const int sr = (rl ^ (rl >> 2)) & 3;
    sp[j] = base[p] + (size_t)(rb0[p] + rl)*2048 + kb + ((pg ^ sr)*8);
  }
  ushort_t* lb[4];
#pragma unroll
  for (int s = 0; s < 4; ++s)
    lb[s] = LDS + 8192 + wv*16384 + s*4096;   // FIX: slot stride 4096 us

  auto MISSUE = [&](int c){
    ushort_t* B = lb[c & 3];
    const int ko = c*32;
#pragma unroll
    for (int j = 0; j < 8; ++j){
      const int p = j >> 1, sub = j & 1;
      if (p < 2) stage16 (sp[j] + ko, B + p*1024 + sub*512 + lane*8);
      else       stage16c(sp[j] + ko, B + p*1024 + sub*512 + lane*8);
    }
  };
  MISSUE(0); MISSUE(1); MISSUE(2); MISSUE(3);

  f32x4 acc[2][2] = {};
  const int lg = lane >> 4;                // logical k-granule
  for (int c = 0; c < 16; ++c){
    if      (c <= 12) { WAITVM(24); }
    else if (c == 13) { WAITVM(16); }
    else if (c == 14) { WAITVM(8); }
    else              { WAITVM(0); }
    const ushort_t* B = lb[c & 3];
    bfx8 wf[2][2], af[2][2];
#pragma unroll
    for (int m = 0; m < 2; ++m){
      const int rl = m*16 + (lane & 15);
      const int sr = (rl ^ (rl >> 2)) & 3;
      const int off = rl*32 + ((lg ^ sr)*8);
      wf[0][m] = *(const bfx8*)(B + off);
      wf[1][m] = *(const bfx8*)(B + 1024 + off);
      af[0][m] = *(const bfx8*)(B + 2048 + off);
      af[1][m] = *(const bfx8*)(B + 3072 + off);
    }
    WAITLG(0);
    if (c < 12) MISSUE(c + 4);
#pragma unroll
    for (int m = 0; m < 2; ++m)
#pragma unroll
      for (int n = 0; n < 2; ++n){
        acc[m][n] = MFMA(wf[0][m], af[0][n], acc[m][n]);
        acc[m][n] = MFMA(wf[0][m], af[1][n], acc[m][n]);
        acc[m][n] = MFMA(wf[1][m], af[0][n], acc[m][n]);
      }
  }

  // partial combine via LDS (f32, 16 KB at byte 0)
  float* PL = (float*)LDS;
#pragma unroll
  for (int m = 0; m < 2; ++m)
#pragma unroll
    for (int n = 0; n < 2; ++n)
#pragma unroll
      for (int r = 0; r < 4; ++r)
        PL[wv*1024 + (m*2 + n)*256 + r*64 + lane] = acc[m][n][r];
  __syncthreads();
  for (int o = tid; o < 1024; o += 256){
    float s = PL[o] + PL[1024 + o] + PL[2048 + o] + PL[3072 + o];
    const int m = o >> 9, n = (o >> 8) & 1, r = (o >> 6) & 3, l = o & 63;
    const int d = d0 + m*16 + (l >> 4)*4 + r;
    const int b = b0 + n*16 + (l & 15);
    s += mb[d];
    dout[((size_t)b*128 + t)*256 + d] = s;
    const unsigned short hv = f2bf(s);
    sth2(&inph[(size_t)b*256 + d], hv);
    sth2(&inpl[(size_t)b*256 + d], f2bf(s - bf2f(hv)));
  }
}

// WG -> (dir, rowgroup, b-half); b-halves 8 apart => XCD co-location.
__device__ __forceinline__ void wg_decode(int wg, int& dir, int& r0, int& n0,
                                          int& b0, int& me){
  const int half = (wg >> 3) & 1;
  const int rgd  = (wg & 7) | ((wg >> 4) << 3);        // 0..127
  dir = rgd >> 6;
  const int rg = rgd & 63;
  r0 = rg * 64; n0 = rg * 16; b0 = half * 64;
  me = (rg << 1) | half;                               // 0..127 within dir
}

// Build the W-prefetch descriptor (chunks 4,5 into W slots 0,1).
__device__ __forceinline__ WPre make_wpre(const ushort_t* WhH, const ushort_t* WhL,
                                          int r0, ushort_t* LDS){
  const int tid = threadIdx.x, lane = tid & 63, wv = tid >> 6;
  const int srw = lane >> 3;
  const int sg  = (lane & 7) ^ srw;
  WPre w;
  w.active = (wv < 2);
  const ushort_t* sb = (wv == 1) ? WhL : WhH;
#pragma unroll
  for (int j = 0; j < 8; ++j)
    w.pj[j] = sb + (size_t)(r0 + j*8 + srw)*1024 + sg*8;
#pragma unroll
  for (int s = 0; s < 2; ++s)
    w.ldsb[s] = LDS + 16384 + s*8192 + (wv & 1)*4096;
  return w;
}

__global__ void __launch_bounds__(256) rnn_enc_kernel(
    const float* __restrict__ Wih_f, const float* __restrict__ b_f,
    const float* __restrict__ Wih_b, const float* __restrict__ b_b,
    const ushort_t* __restrict__ WhhH, const ushort_t* __restrict__ WhhL,
    const float* __restrict__ x,
    ushort_t* __restrict__ Hh, ushort_t* __restrict__ Hl,
    float* __restrict__ C, unsigned* flagsE)
{
  extern __shared__ ushort_t LDS[];
  int dir, r0, n0, b0, me;
  wg_decode(blockIdx.x, dir, r0, n0, b0, me);
  const float* Wih = dir ? Wih_b : Wih_f;
  const float* bia = dir ? b_b : b_f;
  const ushort_t* WhH = WhhH + (size_t)dir*4096*1024;
  const ushort_t* WhL = WhhL + (size_t)dir*4096*1024;
  unsigned* fl = flagsE + dir*128;
  const WPre wp = make_wpre(WhH, WhL, r0, LDS);

  float creg[2][2] = {{0.f, 0.f}, {0.f, 0.f}};
  wpre_issue(wp);                           // t=0 W prologue
  for (int t = 0; t < 256; ++t){
    const int tt = dir ? (255 - t) : t;
    const int rp = t & 1;
    cell_step<1>(Wih, WhH, WhL, bia,
                 x + (size_t)tt*256, nullptr, nullptr,
                 Hh + (size_t)rp     *262144 + dir*1024,
                 Hl + (size_t)rp     *262144 + dir*1024,
                 Hh + (size_t)(rp^1) *262144 + dir*1024,
                 Hl + (size_t)(rp^1) *262144 + dir*1024,
                 creg, r0, n0, b0, LDS);
    bar_pf(fl, 128, me, (unsigned)(t + 1), wp, t < 255);
  }
  // hand off c-state to decoder (cross-kernel boundary flushes)
  {
    const int lane = threadIdx.x & 63, wv = threadIdx.x >> 6;
    const int wm = wv >> 1, wn = wv & 1, cb = lane >> 4, fr = lane & 15;
    float* Cst = C + (size_t)dir*1024*128;
#pragma unroll
    for (int m = 0; m < 2; ++m)
#pragma unroll
      for (int nb = 0; nb < 2; ++nb){
        const int n = n0 + wm*8 + m*4 + cb;
        const int b = b0 + wn*32 + nb*16 + fr;
        Cst[n*128 + b] = creg[m][nb];
      }
  }
}

__global__ void __launch_bounds__(256) rnn_dec_kernel(
    const float* __restrict__ Wih_f, const float* __restrict__ b_f,
    const float* __restrict__ Wih_b, const float* __restrict__ b_b,
    const ushort_t* __restrict__ WhhH, const ushort_t* __restrict__ WhhL,
    const ushort_t* __restrict__ mWh, const ushort_t* __restrict__ mWl,
    const float* __restrict__ mb,
    ushort_t* __restrict__ Hh, ushort_t* __restrict__ Hl,
    float* __restrict__ C,
    ushort_t* __restrict__ inph, ushort_t* __restrict__ inpl,
    float* __restrict__ dout, unsigned* flagsD)
{
  extern __shared__ ushort_t LDS[];
  const int wg = blockIdx.x;
  int dir, r0, n0, b0, me;
  wg_decode(wg, dir, r0, n0, b0, me);
  const float* Wih = dir ? Wih_b : Wih_f;
  const float* bia = dir ? b_b : b_f;
  const ushort_t* WhH = WhhH + (size_t)dir*4096*1024;
  const ushort_t* WhL = WhhL + (size_t)dir*4096*1024;
  const WPre wp = make_wpre(WhH, WhL, r0, LDS);

  float creg[2][2];
  {
    const int lane = threadIdx.x & 63, wv = threadIdx.x >> 6;
    const int wm = wv >> 1, wn = wv & 1, cb = lane >> 4, fr = lane & 15;
    const float* Cst = C + (size_t)dir*1024*128;
#pragma unroll
    for (int m = 0; m < 2; ++m)
#pragma unroll
      for (int nb = 0; nb < 2; ++nb){
        const int n = n0 + wm*8 + m*4 + cb;
        const int b = b0 + wn*32 + nb*16 + fr;
        creg[m][nb] = Cst[n*128 + b];
      }
  }
  wpre_issue(wp);                           // t=0 W prologue
  for (int t = 0; t < 128; ++t){
    const int rp = t & 1;
    cell_step<0>(Wih, WhH, WhL, bia,
                 nullptr, inph, inpl,
                 Hh + (size_t)rp     *262144 + dir*1024,
                 Hl + (size_t)rp     *262144 + dir*1024,
                 Hh + (size_t)(rp^1) *262144 + dir*1024,
                 Hl + (size_t)(rp^1) *262144 + dir*1024,
                 creg, r0, n0, b0, LDS);
    bar(flagsD, 256, wg, (unsigned)(2*t + 1));
    if (wg < 32)
      mlp32(Hh + (size_t)(rp^1)*262144, Hl + (size_t)(rp^1)*262144,
            mWh, mWl, mb, dout, inph, inpl, wg, t, LDS);
    bar_pf(flagsD, 256, wg, (unsigned)(2*t + 2), wp, t < 127);
  }
}

// ---------------------------------------------------------------------------
// Prep kernels
// ---------------------------------------------------------------------------
__global__ void k_wplanes(ushort_t* Hp, ushort_t* Lp,
                          const float* Whh_f, const float* Whh_b)
{
  const size_t N = 2ull*4096*1024;
  for (size_t i = (size_t)blockIdx.x*blockDim.x + threadIdx.x; i < N;
       i += (size_t)gridDim.x*blockDim.x){
    int dir = (int)(i >> 22);
    int r   = (int)((i >> 10) & 4095);
    int k   = (int)(i & 1023);
    int n = r >> 2, q = r & 3;
    const float* W = dir ? Whh_b : Whh_f;
    float v = W[(size_t)(q*1024 + n)*1024 + k];
    unsigned short h = f2bf(v);
    Hp[i] = h;
    Lp[i] = f2bf(v - bf2f(h));
  }
}

__global__ void k_init(ushort_t* Hh, ushort_t* Hl,
                       ushort_t* inph, ushort_t* inpl,
                       ushort_t* mWh, ushort_t* mWl,
                       const float* x, const float* mW, unsigned* cnt)
{
  const size_t N = 524288;  // 2 parity * 128 * 2048 == 256*2048 (mlp)
  for (size_t i = (size_t)blockIdx.x*blockDim.x + threadIdx.x; i < N;
       i += (size_t)gridDim.x*blockDim.x){
    Hh[i] = 0; Hl[i] = 0;
    float wv = mW[i];
    unsigned short wh = f2bf(wv);
    mWh[i] = wh;
    mWl[i] = f2bf(wv - bf2f(wh));
    if (i < 32768){
      int b = (int)(i >> 8), d = (int)(i & 255);
      float v = x[((size_t)b*256 + 255)*256 + d];        // x[:, 255, :]
      unsigned short hi = f2bf(v);
      inph[i] = hi;
      inpl[i] = f2bf(v - bf2f(hi));
    }
    if (i < 2048) cnt[i] = 0;
  }
}

// ---------------------------------------------------------------------------
extern "C" void kernel_launch(void* const* d_in, const int* in_sizes, int n_in,
                              void* d_out, int out_size, void* d_ws, size_t ws_size,
                              hipStream_t stream)
{
  (void)in_sizes; (void)n_in; (void)out_size; (void)ws_size;
  const float* x      = (const float*)d_in[0];
  const float* eWih_f = (const float*)d_in[2];
  const float* eWhh_f = (const float*)d_in[3];
  const float* eb_f   = (const float*)d_in[4];
  const float* eWih_b = (const float*)d_in[5];
  const float* eWhh_b = (const float*)d_in[6];
  const float* eb_b   = (const float*)d_in[7];
  const float* dWih_f = (const float*)d_in[8];
  const float* dWhh_f = (const float*)d_in[9];
  const float* db_f   = (const float*)d_in[10];
  const float* dWih_b = (const float*)d_in[11];
  const float* dWhh_b = (const float*)d_in[12];
  const float* db_b   = (const float*)d_in[13];
  const float* mW     = (const float*)d_in[14];
  const float* mb     = (const float*)d_in[15];

  char* p = (char*)d_ws;
  size_t off = 0;
  unsigned* cnt   = (unsigned*)(p + off);  off += 8192;
  ushort_t* WhhEh = (ushort_t*)(p + off);  off += 16777216;
  ushort_t* WhhEl = (ushort_t*)(p + off);  off += 16777216;
  ushort_t* WhhDh = (ushort_t*)(p + off);  off += 16777216;
  ushort_t* WhhDl = (ushort_t*)(p + off);  off += 16777216;
  ushort_t* mWh   = (ushort_t*)(p + off);  off += 1048576;
  ushort_t* mWl   = (ushort_t*)(p + off);  off += 1048576;
  ushort_t* Hh    = (ushort_t*)(p + off);  off += 1048576;
  ushort_t* Hl    = (ushort_t*)(p + off);  off += 1048576;
  float*    C     = (float*)(p + off);     off += 1048576;
  ushort_t* inph  = (ushort_t*)(p + off);  off += 65536;
  ushort_t* inpl  = (ushort_t*)(p + off);  off += 65536;

  unsigned* flagsD = cnt;              // 256
  unsigned* flagsE = cnt + 256;        // 2 x 128

  hipFuncSetAttribute(reinterpret_cast<const void*>(rnn_enc_kernel),
                      hipFuncAttributeMaxDynamicSharedMemorySize, 147456);
  hipFuncSetAttribute(reinterpret_cast<const void*>(rnn_dec_kernel),
                      hipFuncAttributeMaxDynamicSharedMemorySize, 147456);

  k_init   <<<512, 256, 0, stream>>>(Hh, Hl, inph, inpl, mWh, mWl, x, mW, cnt);
  k_wplanes<<<2048, 256, 0, stream>>>(WhhEh, WhhEl, eWhh_f, eWhh_b);
  k_wplanes<<<2048, 256, 0, stream>>>(WhhDh, WhhDl, dWhh_f, dWhh_b);

  rnn_enc_kernel<<<NWG, 256, 147456, stream>>>(eWih_f, eb_f, eWih_b, eb_b,
                                               WhhEh, WhhEl, x, Hh, Hl, C, flagsE);
  rnn_dec_kernel<<<NWG, 256, 147456, stream>>>(dWih_f, db_f, dWih_b, db_b,
                                               WhhDh, WhhDl, mWh, mWl, mb,
                                               Hh, Hl, C, inph, inpl,
                                               (float*)d_out, flagsD);
}